// Round 13
// baseline (131.065 us; speedup 1.0000x reference)
//
#include <hip/hip_runtime.h>

// ---------------------------------------------------------------------------
// DeepLagrangianNetwork head — round 17: cross-iteration software pipelining.
// The last untested mechanism: in R6/R7/R9 the single h1 LDS buffer + loop
// structure serialized phase-1(itr+1) behind phase-2(itr) — two streams in
// DIFFERENT basic blocks, invisible to the list scheduler. This round:
//   - double-buffered h1 (buf = itr&1), 128-thr blocks (2 waves) so the
//     double buffer is 32 KiB (5 blocks/CU possible)
//   - phase-1(itr+1) chunks textually interleaved with phase-2(itr) it-tiles
//     in ONE basic block: ~440 independent VALU ops fill phase-2's
//     ds_read/MFMA/shuffle stalls
//   - WAR safety: body itr writes buf[(itr+1)&1], which was last read in
//     body itr-1; per-wave DS ops execute in program order -> no hazard,
//     still zero barriers (wave-self-contained)
// Everything else verbatim from the champion (R9): x prefetch chain, W2 A
// fragments + head weights register-resident, MFMA phase-2, pk-fma heads,
// quad shfl_xor reduce, coalesced float4 store. Arithmetic bit-identical.
// NO launch_bounds min-waves clause (64-VGPR clamp + spill; R6/R8).
// Fragment layouts (m89/m120-verified):
//   A[m=lane&15][k=(lane>>4)*8+j]   B[k=(lane>>4)*8+j][n=lane&15]
//   C: col(n)=lane&15, row(m)=(lane>>4)*4+reg
// ---------------------------------------------------------------------------

typedef __attribute__((ext_vector_type(8))) short bf16x8;
typedef __attribute__((ext_vector_type(4))) float f32x4;
typedef __attribute__((ext_vector_type(2))) float f32x2;

#define BLOCK_THREADS 128       // 2 waves
#define GRID_BLOCKS   2048      // x 128 rows x 4 iters = 1048576 rows

__device__ __forceinline__ float lrelu(float a) {
    return fmaxf(a, 0.01f * a);     // exact leaky_relu(0.01)
}

__device__ __forceinline__ f32x2 lrelu2(f32x2 a) {
    return __builtin_elementwise_max(a, a * 0.01f);   // v_pk_mul + v_pk_max
}

__device__ __forceinline__ float softplus(float v) {
    return fmaxf(v, 0.0f) + log1pf(expf(-fabsf(v)));   // jax.nn.softplus
}

// two fp32 -> packed bf16x2 (hardware RNE), 1 VALU op.
__device__ __forceinline__ unsigned cvt_pk_bf16(float lo, float hi) {
    unsigned r;
    asm("v_cvt_pk_bf16_f32 %0, %1, %2" : "=v"(r) : "v"(lo), "v"(hi));
    return r;
}

__global__ __launch_bounds__(BLOCK_THREADS) void dln_mfma(
    const float* __restrict__ x,
    const float* __restrict__ W1,  const float* __restrict__ b1,
    const float* __restrict__ W2,  const float* __restrict__ b2,
    const float* __restrict__ WLd, const float* __restrict__ bLd,
    const float* __restrict__ WLo, const float* __restrict__ bLo,
    float* __restrict__ out,
    int iters, int iter_stride)
{
    // [buf][wave][chunk][row][8 bf16] = 32 KiB double buffer
    __shared__ __align__(16) unsigned short h1s[2][2][8][64][8];

    const int tid  = threadIdx.x;
    const int lane = tid & 63;
    const int wv   = tid >> 6;          // wave id 0..1
    const int quad = lane >> 4;         // 0..3
    const int c    = lane & 15;         // 0..15

    int row = blockIdx.x * BLOCK_THREADS + tid;
    const float4 q0 = ((const float4*)x)[row];      // x rows of itr 0

    // ---- preload (once per block): W2 A-frags (bf16), head weights, b2 ----
    bf16x8 afrag[4][2];
    f32x4 wld0[4], wld1[4], wlo[4], b2v[4];
#pragma unroll
    for (int mt = 0; mt < 4; ++mt) {
        const float* wr = W2 + (16 * mt + c) * 64 + 8 * quad;
#pragma unroll
        for (int s = 0; s < 2; ++s) {
            const float4 f0 = *(const float4*)(wr + 32 * s);
            const float4 f1 = *(const float4*)(wr + 32 * s + 4);
            uint4 u;
            u.x = cvt_pk_bf16(f0.x, f0.y);
            u.y = cvt_pk_bf16(f0.z, f0.w);
            u.z = cvt_pk_bf16(f1.x, f1.y);
            u.w = cvt_pk_bf16(f1.z, f1.w);
            afrag[mt][s] = __builtin_bit_cast(bf16x8, u);
        }
        const int nb = 16 * mt + 4 * quad;   // this lane's 16 neurons
        wld0[mt] = *(const f32x4*)(WLd + nb);
        wld1[mt] = *(const f32x4*)(WLd + 64 + nb);
        wlo[mt]  = *(const f32x4*)(WLo + nb);
        b2v[mt]  = *(const f32x4*)(b2 + nb);
    }
    const float bld0 = bLd[0];
    const float bld1 = bLd[1];
    const float blo0 = bLo[0];

    // ---- phase-1 for one chunk: h1 row `lane`, chunk ch -> LDS wbuf -------
    auto P1 = [&](int wbuf, const float4& qv, int ch) {
        unsigned up[4];
#pragma unroll
        for (int p = 0; p < 4; ++p) {
            float h[2];
#pragma unroll
            for (int e = 0; e < 2; ++e) {
                const int j = ch * 8 + p * 2 + e;
                float a = b1[j];
                a = fmaf(qv.x, W1[4 * j + 0], a);
                a = fmaf(qv.y, W1[4 * j + 1], a);
                a = fmaf(qv.z, W1[4 * j + 2], a);
                a = fmaf(qv.w, W1[4 * j + 3], a);
                h[e] = lrelu(a);
            }
            up[p] = cvt_pk_bf16(h[0], h[1]);
        }
        *(uint4*)&h1s[wbuf][wv][ch][lane][0] = make_uint4(up[0], up[1], up[2], up[3]);
    };

    // ---- phase-2 for one 16-row tile: MFMA + in-register heads ------------
    auto P2IT = [&](int rbuf, int it, float& d0, float& d1, float& d2) {
        const bf16x8 bf0 = *(const bf16x8*)&h1s[rbuf][wv][quad][it * 16 + c][0];
        const bf16x8 bf1 = *(const bf16x8*)&h1s[rbuf][wv][4 + quad][it * 16 + c][0];
        f32x2 pld0 = {0.0f, 0.0f}, pld1 = {0.0f, 0.0f}, plo = {0.0f, 0.0f};
#pragma unroll
        for (int mt = 0; mt < 4; ++mt) {
            f32x4 acc = b2v[mt];                // bias pre-load
            acc = __builtin_amdgcn_mfma_f32_16x16x32_bf16(afrag[mt][0], bf0, acc, 0, 0, 0);
            acc = __builtin_amdgcn_mfma_f32_16x16x32_bf16(afrag[mt][1], bf1, acc, 0, 0, 0);
            const f32x2 hlo = lrelu2((f32x2){acc[0], acc[1]});
            const f32x2 hhi = lrelu2((f32x2){acc[2], acc[3]});
            pld0 = __builtin_elementwise_fma(hlo, (f32x2){wld0[mt][0], wld0[mt][1]}, pld0);
            pld0 = __builtin_elementwise_fma(hhi, (f32x2){wld0[mt][2], wld0[mt][3]}, pld0);
            pld1 = __builtin_elementwise_fma(hlo, (f32x2){wld1[mt][0], wld1[mt][1]}, pld1);
            pld1 = __builtin_elementwise_fma(hhi, (f32x2){wld1[mt][2], wld1[mt][3]}, pld1);
            plo  = __builtin_elementwise_fma(hlo, (f32x2){wlo[mt][0],  wlo[mt][1]},  plo);
            plo  = __builtin_elementwise_fma(hhi, (f32x2){wlo[mt][2],  wlo[mt][3]},  plo);
        }
        float r0 = pld0[0] + pld0[1];
        float r1 = pld1[0] + pld1[1];
        float r2 = plo[0]  + plo[1];
        r0 += __shfl_xor(r0, 16); r0 += __shfl_xor(r0, 32);
        r1 += __shfl_xor(r1, 16); r1 += __shfl_xor(r1, 32);
        r2 += __shfl_xor(r2, 16); r2 += __shfl_xor(r2, 32);
        if (it == quad) { d0 = r0; d1 = r1; d2 = r2; }
    };

    auto EPI = [&](int row_out, float sld0, float sld1, float slo) {
        const float ld0 = softplus(sld0 + bld0);
        const float ld1 = softplus(sld1 + bld1);
        const float lo  = slo + blo0;
        float4 o;
        o.x = fmaf(ld0, ld0, 1e-9f);                  // H00
        o.y = ld0 * lo;                               // H01
        o.z = o.y;                                    // H10
        o.w = fmaf(lo, lo, fmaf(ld1, ld1, 1e-9f));    // H11
        reinterpret_cast<float4*>(out)[row_out] = o;
    };

    // ---- prologue: phase-1 of itr 0 into buf 0 ----------------------------
#pragma unroll
    for (int ch = 0; ch < 8; ++ch) P1(0, q0, ch);
    float4 qnext = ((const float4*)x)[(iters > 1) ? row + iter_stride : row];

    // ---- pipelined main loop: phase-2(itr) ∥ phase-1(itr+1) ---------------
    for (int itr = 0; itr < iters - 1; ++itr) {
        const float4 qp1 = qnext;            // x rows of itr+1
        const int row_cur = row;             // out rows of itr
        row += iter_stride;                  // rows of itr+1
        const int rload = (itr + 2 < iters) ? row + iter_stride : row;
        qnext = ((const float4*)x)[rload];   // prefetch x of itr+2 (clamped)
        const int rbuf = itr & 1;
        const int wbuf = rbuf ^ 1;

        float sld0 = 0.0f, sld1 = 0.0f, slo = 0.0f;
        // one basic block, both streams visible to the scheduler:
        P1(wbuf, qp1, 0); P1(wbuf, qp1, 1); P2IT(rbuf, 0, sld0, sld1, slo);
        P1(wbuf, qp1, 2); P1(wbuf, qp1, 3); P2IT(rbuf, 1, sld0, sld1, slo);
        P1(wbuf, qp1, 4); P1(wbuf, qp1, 5); P2IT(rbuf, 2, sld0, sld1, slo);
        P1(wbuf, qp1, 6); P1(wbuf, qp1, 7); P2IT(rbuf, 3, sld0, sld1, slo);

        EPI(row_cur, sld0, sld1, slo);
    }

    // ---- final iteration: phase-2 only ------------------------------------
    {
        const int rbuf = (iters - 1) & 1;
        float sld0 = 0.0f, sld1 = 0.0f, slo = 0.0f;
        P2IT(rbuf, 0, sld0, sld1, slo);
        P2IT(rbuf, 1, sld0, sld1, slo);
        P2IT(rbuf, 2, sld0, sld1, slo);
        P2IT(rbuf, 3, sld0, sld1, slo);
        EPI(row, sld0, sld1, slo);
    }
}

// ---- scalar fallback for tail rows ----------------------------------------
__global__ __launch_bounds__(256) void dln_tail(
    const float* __restrict__ x,
    const float* __restrict__ W1,  const float* __restrict__ b1,
    const float* __restrict__ W2,  const float* __restrict__ b2,
    const float* __restrict__ WLd, const float* __restrict__ bLd,
    const float* __restrict__ WLo, const float* __restrict__ bLo,
    float* __restrict__ out, int row0, int nrows)
{
    const int row = row0 + blockIdx.x * 256 + threadIdx.x;
    if (row >= nrows) return;
    const float4 qv = reinterpret_cast<const float4*>(x)[row];
    float h1[64];
#pragma unroll
    for (int j = 0; j < 64; ++j) {
        float a = b1[j];
        a = fmaf(qv.x, W1[4 * j + 0], a);
        a = fmaf(qv.y, W1[4 * j + 1], a);
        a = fmaf(qv.z, W1[4 * j + 2], a);
        a = fmaf(qv.w, W1[4 * j + 3], a);
        h1[j] = lrelu(a);
    }
    float ld0 = bLd[0], ld1 = bLd[1], lo = bLo[0];
#pragma unroll 4
    for (int j = 0; j < 64; ++j) {
        float a0 = b2[j], a1 = 0.0f;
        const float* w = W2 + 64 * j;
#pragma unroll
        for (int k = 0; k < 64; k += 2) {
            a0 = fmaf(h1[k],     w[k],     a0);
            a1 = fmaf(h1[k + 1], w[k + 1], a1);
        }
        const float a = lrelu(a0 + a1);
        ld0 = fmaf(a, WLd[j],      ld0);
        ld1 = fmaf(a, WLd[64 + j], ld1);
        lo  = fmaf(a, WLo[j],      lo);
    }
    ld0 = softplus(ld0);
    ld1 = softplus(ld1);
    float4 o;
    o.x = fmaf(ld0, ld0, 1e-9f);
    o.y = ld0 * lo;
    o.z = o.y;
    o.w = fmaf(lo, lo, fmaf(ld1, ld1, 1e-9f));
    reinterpret_cast<float4*>(out)[row] = o;
}

extern "C" void kernel_launch(void* const* d_in, const int* in_sizes, int n_in,
                              void* d_out, int out_size, void* d_ws, size_t ws_size,
                              hipStream_t stream)
{
    const float* x   = (const float*)d_in[0];
    const float* W1  = (const float*)d_in[1];
    const float* b1  = (const float*)d_in[2];
    const float* W2  = (const float*)d_in[3];
    const float* b2  = (const float*)d_in[4];
    const float* WLd = (const float*)d_in[5];
    const float* bLd = (const float*)d_in[6];
    const float* WLo = (const float*)d_in[7];
    const float* bLo = (const float*)d_in[8];
    float* out = (float*)d_out;

    const int nrows  = in_sizes[0] / 4;             // x is (nrows, 4) fp32
    const int stripe = GRID_BLOCKS * BLOCK_THREADS; // 262144 rows / stripe
    const int iters  = nrows / stripe;
    const int nfull  = iters * stripe;
    const int rem    = nrows - nfull;

    if (iters > 0)
        dln_mfma<<<GRID_BLOCKS, BLOCK_THREADS, 0, stream>>>(
            x, W1, b1, W2, b2, WLd, bLd, WLo, bLo, out, iters, stripe);
    if (rem > 0)
        dln_tail<<<(rem + 255) / 256, 256, 0, stream>>>(
            x, W1, b1, W2, b2, WLd, bLd, WLo, bLo, out, nfull, nrows);
}